// Round 17
// baseline (1357.376 us; speedup 1.0000x reference)
//
#include <hip/hip_runtime.h>

#define MBn 2
#define Cn 3
#define Mn 256
#define Nn 256
#define Pn 32
#define IMG   65536      // M*N
#define CIMG  196608     // C*M*N
#define XSZ   393216     // MB*C*M*N
#define ASZ   12582912   // MB*P*C*M*N
#define EPSf  1e-8f
#define NSTEP 10

#define NCV  1536    // 8 pg x 32 tiles(64x32) x 6 cm
#define RST  46      // rr LDS stride (76 rows x 44 cols used)
#define AST  40      // a_new LDS stride (70 rows x 38 cols used)

// ---------------- init: x0 = convT_fil(z, fil) (fil symmetric => conv == convT) ----------------
__global__ __launch_bounds__(256) void k_x0(const float* __restrict__ z, const float* __restrict__ fil,
                                            float* __restrict__ x0, float* __restrict__ x0c) {
    int idx = blockIdx.x * 256 + threadIdx.x;
    if (idx >= XSZ) return;
    int j = idx & 255, i = (idx >> 8) & 255, cm = idx >> 16;
    const float* zc = z + cm * IMG;
    float acc = 0.f;
    #pragma unroll
    for (int u = 0; u < 5; ++u) {
        int ii = i + 2 - u;
        if ((unsigned)ii >= (unsigned)Mn) continue;
        #pragma unroll
        for (int v = 0; v < 5; ++v) {
            int jj = j + 2 - v;
            if ((unsigned)jj >= (unsigned)Nn) continue;
            acc += fil[u * 5 + v] * zc[ii * Nn + jj];
        }
    }
    x0[idx] = acc;
    x0c[idx] = acc;
}

// ---------------- K1a (step 0 only): Bap = conv_CSC(a_init, B) partials ----------------
// 64x32 tile, 4x2 per thread, 4 p per block. grid: 8 pg x 32 tiles x 6 cm = 1536.
__global__ __launch_bounds__(256) void k_conv0(const float* __restrict__ a_src, const float* __restrict__ Bg,
                                               float* __restrict__ Bap) {
    __shared__ float ans[70 * AST];
    int blk = blockIdx.x;
    int tid = threadIdx.x;
    int pg   = blk & 7;
    int tile = (blk >> 3) & 31;
    int cm   = blk >> 8;            // 0..5
    int c = cm % Cn, mb = cm / Cn;
    int i0 = (tile >> 3) * 64, j0 = (tile & 7) * 32;
    int tx = tid & 15, ty = tid >> 4;

    float acc[8];
    #pragma unroll
    for (int k = 0; k < 8; ++k) acc[k] = 0.f;

    #pragma unroll 1
    for (int pi = 0; pi < 4; ++pi) {
        int p = pg * 4 + pi;
        const float* ap = a_src + ((size_t)(mb * Pn + p) * Cn + c) * IMG;
        for (int l = tid; l < 70 * 38; l += 256) {
            int r = l / 38, cc = l - r * 38;
            int gi = i0 + r - 3, gj = j0 + cc - 3;
            float v = 0.f;
            if ((unsigned)gi < 256u && (unsigned)gj < 256u) v = ap[gi * Nn + gj];
            ans[r * AST + cc] = v;
        }
        __syncthreads();
        const float* bq = Bg + (p * Cn + c) * 49;
        #pragma unroll
        for (int r = 0; r < 10; ++r) {
            float w[8];
            const float* rowp = ans + (4 * ty + r) * AST + 2 * tx;
            #pragma unroll
            for (int k = 0; k < 4; ++k) {
                float2 t = *(const float2*)(rowp + 2 * k);
                w[2 * k] = t.x; w[2 * k + 1] = t.y;
            }
            #pragma unroll
            for (int ri = 0; ri < 4; ++ri) {
                int u = r - ri;
                if (u >= 0 && u <= 6) {
                    #pragma unroll
                    for (int v = 0; v < 7; ++v) {
                        float b = bq[u * 7 + v];
                        acc[ri * 2]     += w[v]     * b;
                        acc[ri * 2 + 1] += w[v + 1] * b;
                    }
                }
            }
        }
        __syncthreads();
    }
    float* out = Bap + pg * XSZ + cm * IMG;
    #pragma unroll
    for (int ri = 0; ri < 4; ++ri) {
        float2 st; st.x = acc[ri * 2]; st.y = acc[ri * 2 + 1];
        *(float2*)(out + (i0 + 4 * ty + ri) * Nn + j0 + 2 * tx) = st;
    }
}

// ---------------- K1b (steps 1..9): fused a-update + Ba ----------------
// a_new(p) = soft(a_old(p) + g2*convT(rr)) computed over 70x38 halo region in LDS,
// interior 64x32 written to a_out, then Ba partial accumulated from LDS.
// grid: 1536 + 2 norm blocks. pstep = s-1 (params for the a-update).
__global__ __launch_bounds__(256) void k_convA(const float* __restrict__ a_old, float* __restrict__ a_out,
                                               const float* __restrict__ rr, const float* __restrict__ Bg,
                                               float* __restrict__ Bap,
                                               const float* __restrict__ lam1, const float* __restrict__ gam2,
                                               int pstep,
                                               const float* __restrict__ part, float* __restrict__ scale2) {
    __shared__ float rrs[76 * RST];
    __shared__ float ans[70 * AST];
    int blk = blockIdx.x;
    int tid = threadIdx.x;

    if (blk >= NCV) {             // ---- norm reduce branch: part -> scale2 ----
        float* red = rrs;
        int mbi = blk - NCV;
        float s = 0.f;
        for (int l = tid; l < 1536; l += 256) {
            int cmq = l >> 8;      // partial index l maps blocks 0..1535 of y12
            (void)cmq;
            s += 0.f;
        }
        // y12 partials: 1536 entries, first 768 are mb=0? No: y12 blk covers idx linear;
        // idx >= CIMG -> mb=1. blocks 0..767 = mb0, 768..1535 = mb1.
        s = 0.f;
        for (int l = tid; l < 768; l += 256) s += part[mbi * 768 + l];
        red[tid] = s;
        __syncthreads();
        #pragma unroll
        for (int k = 128; k > 0; k >>= 1) {
            if (tid < k) red[tid] += red[tid + k];
            __syncthreads();
        }
        if (tid == 0) {
            float nrm = sqrtf(red[0]);
            float radius = 0.05f * sqrtf((float)CIMG);
            scale2[mbi] = fminf(1.f, radius / fmaxf(nrm, EPSf));
        }
        return;
    }

    int pg   = blk & 7;
    int tile = (blk >> 3) & 31;
    int cm   = blk >> 8;            // 0..5
    int c = cm % Cn, mb = cm / Cn;
    int i0 = (tile >> 3) * 64, j0 = (tile & 7) * 32;
    int tx = tid & 15, ty = tid >> 4;

    // stage rr halo: image rows i0-6..i0+69, cols j0-6..j0+37
    const float* rp = rr + cm * IMG;
    for (int l = tid; l < 76 * 44; l += 256) {
        int r = l / 44, cc = l - r * 44;
        int gi = i0 + r - 6, gj = j0 + cc - 6;
        float v = 0.f;
        if ((unsigned)gi < 256u && (unsigned)gj < 256u) v = rp[gi * Nn + gj];
        rrs[r * RST + cc] = v;
    }
    __syncthreads();

    float g2 = gam2[pstep], thr = g2 * lam1[pstep];

    float acc[8];
    #pragma unroll
    for (int k = 0; k < 8; ++k) acc[k] = 0.f;

    #pragma unroll 1
    for (int pi = 0; pi < 4; ++pi) {
        int p = pg * 4 + pi;
        const float* bq = Bg + (p * Cn + c) * 49;
        const float* ap = a_old + ((size_t)(mb * Pn + p) * Cn + c) * IMG;
        float* aw = a_out + ((size_t)(mb * Pn + p) * Cn + c) * IMG;

        // ---- phase A: a_new over 70x38 ext region -> ans ----
        // segment = 1 row x 10 cols (last segment 8 cols); 280 segments.
        for (int seg = tid; seg < 280; seg += 256) {
            int r  = seg >> 2;
            int sc = seg & 3;
            int c0 = sc * 10;
            float av[10];
            #pragma unroll
            for (int k = 0; k < 10; ++k) av[k] = 0.f;
            #pragma unroll
            for (int u = 0; u < 7; ++u) {
                float w2[16];
                const float* rowp = rrs + (r + u) * RST + c0;
                #pragma unroll
                for (int k = 0; k < 8; ++k) {
                    float2 t = *(const float2*)(rowp + 2 * k);
                    w2[2 * k] = t.x; w2[2 * k + 1] = t.y;
                }
                #pragma unroll
                for (int v = 0; v < 7; ++v) {
                    float b = bq[(6 - u) * 7 + (6 - v)];   // flipped: true convolution
                    #pragma unroll
                    for (int k = 0; k < 10; ++k) av[k] += w2[v + k] * b;
                }
            }
            int W = (sc == 3) ? 8 : 10;
            int gi = i0 - 3 + r;
            bool rowok = ((unsigned)gi < 256u);
            #pragma unroll
            for (int k = 0; k < 10; ++k) {
                if (k < W) {
                    int cc = c0 + k;
                    int gj = j0 - 3 + cc;
                    float val = 0.f;
                    if (rowok && (unsigned)gj < 256u) {
                        float aold = ap[gi * Nn + gj];
                        float t = aold + g2 * av[k];
                        val = copysignf(fmaxf(fabsf(t) - thr, 0.f), t);
                    }
                    ans[r * AST + cc] = val;
                }
            }
        }
        __syncthreads();

        // ---- phase B: Ba partial from ans + interior a write ----
        float2 stv[4];
        #pragma unroll
        for (int r = 0; r < 10; ++r) {
            float w[8];
            const float* rowp = ans + (4 * ty + r) * AST + 2 * tx;
            #pragma unroll
            for (int k = 0; k < 4; ++k) {
                float2 t = *(const float2*)(rowp + 2 * k);
                w[2 * k] = t.x; w[2 * k + 1] = t.y;
            }
            if (r >= 3 && r <= 6) { stv[r - 3].x = w[3]; stv[r - 3].y = w[4]; }
            #pragma unroll
            for (int ri = 0; ri < 4; ++ri) {
                int u = r - ri;
                if (u >= 0 && u <= 6) {
                    #pragma unroll
                    for (int v = 0; v < 7; ++v) {
                        float b = bq[u * 7 + v];       // non-flipped: correlation
                        acc[ri * 2]     += w[v]     * b;
                        acc[ri * 2 + 1] += w[v + 1] * b;
                    }
                }
            }
        }
        #pragma unroll
        for (int ri = 0; ri < 4; ++ri)
            *(float2*)(aw + (size_t)(i0 + 4 * ty + ri) * Nn + j0 + 2 * tx) = stv[ri];
        __syncthreads();
    }

    float* out = Bap + pg * XSZ + cm * IMG;
    #pragma unroll
    for (int ri = 0; ri < 4; ++ri) {
        float2 st; st.x = acc[ri * 2]; st.y = acc[ri * 2 + 1];
        *(float2*)(out + (i0 + 4 * ty + ri) * Nn + j0 + 2 * tx) = st;
    }
}

// ---------------- K2: x update + r + v (y2 finalize folded in) ----------------
__global__ __launch_bounds__(256) void k_xup(const float* __restrict__ xb, const float* __restrict__ Bap,
                                             const float* __restrict__ y1, const float* __restrict__ y2T,
                                             const float* __restrict__ x0c, const float* __restrict__ fil,
                                             const float* __restrict__ gam1, const float* __restrict__ gam3,
                                             const float* __restrict__ scale2, int step,
                                             float* __restrict__ xa, float* __restrict__ rr,
                                             float* __restrict__ vv) {
    int idx = blockIdx.x * 256 + threadIdx.x;
    if (idx >= XSZ) return;
    float g1 = gam1[step];
    int j = idx & 255, i = (idx >> 8) & 255, cm = idx >> 16;
    int mb = cm / Cn, c = cm - mb * Cn;

    float A = 0.f, Bz = 0.f;      // step 0: y2_prev == 0
    if (step > 0) {
        float g3p = gam3[step - 1];
        float invp = 1.f / (g3p + EPSf);
        float sc = scale2[mb];
        A  = 1.f - g3p * invp * sc;
        Bz = -g3p * (1.f - sc);
    }

    const float* y10 = y1 + (mb * 2) * CIMG + c * IMG;
    const float* y11 = y10 + CIMG;
    int im1 = (i == 0) ? Mn - 1 : i - 1;
    int jm1 = (j == 0) ? Nn - 1 : j - 1;
    float dt = y10[im1 * Nn + j] - y10[i * Nn + j] + y11[i * Nn + jm1] - y11[i * Nn + j];

    const float* Tc = y2T + cm * IMG;
    float cf = 0.f;
    #pragma unroll
    for (int u = 0; u < 5; ++u) {
        int ii = i + 2 - u;
        if ((unsigned)ii >= (unsigned)Mn) continue;
        #pragma unroll
        for (int v = 0; v < 5; ++v) {
            int jj = j + 2 - v;
            if ((unsigned)jj >= (unsigned)Nn) continue;
            cf += fil[u * 5 + v] * Tc[ii * Nn + jj];
        }
    }
    cf = A * cf + Bz * x0c[idx];   // conv(y2_aft) = A*conv(T) + Bz*conv(z)

    float bav = 0.f;
    #pragma unroll
    for (int k = 0; k < 8; ++k) bav += Bap[k * XSZ + idx];
    float xv = xb[idx];
    float xn = xv - g1 * (xv - bav + dt + cf);
    xn = fminf(fmaxf(xn, 0.f), 1.f);
    xa[idx] = xn;
    rr[idx] = xv - bav;
    vv[idx] = 2.f * xn - xv;
}

// ---------------- K3: fused y1 update + y2 accumulate (lazy finalize) + partial norms ----------------
__global__ __launch_bounds__(256) void k_y12(float* __restrict__ y1, float* __restrict__ y2T,
                                             const float* __restrict__ vv, const float* __restrict__ fil,
                                             const float* __restrict__ z,
                                             const float* __restrict__ lam2, const float* __restrict__ gam3,
                                             const float* __restrict__ scale2, int step,
                                             float* __restrict__ partial) {
    __shared__ float red[256];
    int tid = threadIdx.x;
    int idx = blockIdx.x * 256 + tid;
    float g3 = gam3[step], l2v = lam2[step];
    int j = idx & 255, i = (idx >> 8) & 255, cm = idx >> 16;
    int mb = cm / Cn, c = cm - mb * Cn;
    const float* vc = vv + cm * IMG;

    float A = 0.f, Bz = 0.f;      // step 0: y2_prev == 0
    if (step > 0) {
        float g3p = gam3[step - 1];
        float invp = 1.f / (g3p + EPSf);
        float sc = scale2[mb];
        A  = 1.f - g3p * invp * sc;
        Bz = -g3p * (1.f - sc);
    }

    int ip1 = (i == Mn - 1) ? 0 : i + 1;
    int jp1 = (j == Nn - 1) ? 0 : j + 1;
    float vij = vc[i * Nn + j];
    float d0 = vc[ip1 * Nn + j] - vij;
    float d1 = vc[i * Nn + jp1] - vij;
    float* y10 = y1 + (mb * 2) * CIMG + c * IMG + i * Nn + j;
    float* y11 = y10 + CIMG;
    float t0 = *y10 + g3 * d0;
    float t1 = *y11 + g3 * d1;
    float inv = 1.f / (g3 + EPSf);
    float w0 = t0 * inv, w1 = t1 * inv;
    float nrm = sqrtf(w0 * w0 + w1 * w1);
    float fac = fmaxf(1.f - (l2v * inv) / fmaxf(nrm, EPSf), 0.f);
    *y10 = t0 - g3 * (w0 * fac);
    *y11 = t1 - g3 * (w1 * fac);

    float cf = 0.f;
    #pragma unroll
    for (int u = 0; u < 5; ++u) {
        int ii2 = i + u - 2;
        if ((unsigned)ii2 >= (unsigned)Mn) continue;
        #pragma unroll
        for (int v = 0; v < 5; ++v) {
            int jj2 = j + v - 2;
            if ((unsigned)jj2 >= (unsigned)Nn) continue;
            cf += fil[u * 5 + v] * vc[ii2 * Nn + jj2];
        }
    }
    float zv = z[idx];
    float t = A * y2T[idx] + Bz * zv + g3 * cf;
    y2T[idx] = t;
    float d = t * inv - zv;
    red[tid] = d * d;
    __syncthreads();
    #pragma unroll
    for (int s = 128; s > 0; s >>= 1) {
        if (tid < s) red[tid] += red[tid + s];
        __syncthreads();
    }
    if (tid == 0) partial[blockIdx.x] = red[0];
}

extern "C" void kernel_launch(void* const* d_in, const int* in_sizes, int n_in,
                              void* d_out, int out_size, void* d_ws, size_t ws_size,
                              hipStream_t stream) {
    const float* z      = (const float*)d_in[0];
    const float* a_init = (const float*)d_in[1];
    const float* B      = (const float*)d_in[2];
    const float* fil    = (const float*)d_in[3];
    const float* lam1   = (const float*)d_in[4];
    const float* lam2   = (const float*)d_in[5];
    const float* gam1   = (const float*)d_in[6];
    const float* gam2   = (const float*)d_in[7];
    const float* gam3   = (const float*)d_in[8];

    float* ws = (float*)d_ws;
    float* a      = ws;                    // ASZ
    float* xA     = a + ASZ;               // XSZ
    float* xB     = xA + XSZ;              // XSZ
    float* x0c    = xB + XSZ;              // XSZ (persistent conv_fil(z))
    float* Bap    = x0c + XSZ;             // 8*XSZ
    float* rr     = Bap + 8 * XSZ;         // XSZ
    float* vv     = rr + XSZ;              // XSZ
    float* y1     = vv + XSZ;              // 2*XSZ
    float* y2T    = y1 + 2 * XSZ;          // XSZ (pre-finalize accumulator T_s)
    float* part   = y2T + XSZ;             // 1536
    float* scale2 = part + 1536;           // 2

    // init
    hipMemsetAsync(y1, 0, (size_t)2 * XSZ * sizeof(float), stream);
    hipMemsetAsync(part, 0, 1536 * sizeof(float), stream);
    k_x0<<<XSZ / 256, 256, 0, stream>>>(z, fil, xA, x0c);

    float* xin = xA;
    float* xout = xB;
    for (int s = 0; s < NSTEP; ++s) {
        if (s == 0) {
            k_conv0<<<NCV, 256, 0, stream>>>(a_init, B, Bap);
        } else {
            const float* a_old = (s == 1) ? a_init : a;
            k_convA<<<NCV + 2, 256, 0, stream>>>(a_old, a, rr, B, Bap, lam1, gam2, s - 1,
                                                 part, scale2);
        }
        k_xup<<<XSZ / 256, 256, 0, stream>>>(xin, Bap, y1, y2T, x0c, fil, gam1, gam3, scale2, s,
                                             xout, rr, vv);
        if (s < NSTEP - 1) {
            k_y12<<<XSZ / 256, 256, 0, stream>>>(y1, y2T, vv, fil, z, lam2, gam3, scale2, s, part);
        }
        float* t = xin; xin = xout; xout = t;
    }

    hipMemcpyAsync(d_out, xin, (size_t)XSZ * sizeof(float), hipMemcpyDeviceToDevice, stream);
}

// Round 18
// 781.743 us; speedup vs baseline: 1.7363x; 1.7363x over previous
//
#include <hip/hip_runtime.h>

#define MBn 2
#define Cn 3
#define Mn 256
#define Nn 256
#define Pn 32
#define IMG   65536      // M*N
#define CIMG  196608     // C*M*N
#define XSZ   393216     // MB*C*M*N
#define ASZ   12582912   // MB*P*C*M*N
#define EPSf  1e-8f
#define NSTEP 10

#define HW 38    // 32+6 halo
#define HP 42    // padded LDS stride (42: row offsets distinct mod 32 across a wave)
#define HSZ (HW * HW)
#define ASTR 42  // aup LDS stride

#define NCONV 3072   // 8 pg x 64 tiles x 6 cm
#define NAUP  6144   // 32 p x 32 tiles(64x32) x 6 cm  (one p per block, 8 outputs/thread)

// ---------------- init: x0 = convT_fil(z, fil) (fil symmetric => conv == convT) ----------------
__global__ __launch_bounds__(256) void k_x0(const float* __restrict__ z, const float* __restrict__ fil,
                                            float* __restrict__ x0, float* __restrict__ x0c) {
    int idx = blockIdx.x * 256 + threadIdx.x;
    if (idx >= XSZ) return;
    int j = idx & 255, i = (idx >> 8) & 255, cm = idx >> 16;
    const float* zc = z + cm * IMG;
    float acc = 0.f;
    #pragma unroll
    for (int u = 0; u < 5; ++u) {
        int ii = i + 2 - u;
        if ((unsigned)ii >= (unsigned)Mn) continue;
        #pragma unroll
        for (int v = 0; v < 5; ++v) {
            int jj = j + 2 - v;
            if ((unsigned)jj >= (unsigned)Nn) continue;
            acc += fil[u * 5 + v] * zc[ii * Nn + jj];
        }
    }
    x0[idx] = acc;
    x0c[idx] = acc;
}

// ---------------- K1: Ba partials = conv_CSC(a, B) + norm-scale branch ----------------
__global__ __launch_bounds__(256, 4) void k_conv(const float* __restrict__ a_in, const float* __restrict__ Bg,
                                                 float* __restrict__ Bap,
                                                 const float* __restrict__ part, float* __restrict__ scale2) {
    __shared__ float buf[2][HW * HP];
    int blk = blockIdx.x;
    int tid = threadIdx.x;

    if (blk >= NCONV) {           // ---- norm reduce branch ----
        float* red = buf[0];
        int mbi = blk - NCONV;
        float s = 0.f;
        for (int l = tid; l < 768; l += 256) s += part[mbi * 768 + l];
        red[tid] = s;
        __syncthreads();
        #pragma unroll
        for (int k = 128; k > 0; k >>= 1) {
            if (tid < k) red[tid] += red[tid + k];
            __syncthreads();
        }
        if (tid == 0) {
            float nrm = sqrtf(red[0]);
            float radius = 0.05f * sqrtf((float)CIMG);
            scale2[mbi] = fminf(1.f, radius / fmaxf(nrm, EPSf));
        }
        return;
    }

    int pg   = blk & 7;
    int tile = (blk >> 3) & 63;
    int cm   = blk >> 9;            // 0..5
    int c = cm % Cn, mb = cm / Cn;
    int i0 = (tile >> 3) * 32, j0 = (tile & 7) * 32;
    int tx = tid & 15, ty = tid >> 4;

    int ldsoff[6]; int goff[6]; bool val[6]; bool wm[6];
    #pragma unroll
    for (int k = 0; k < 6; ++k) {
        int l = tid + 256 * k;
        int r = l / HW, cc = l - r * HW;
        int gi = i0 + r - 3, gj = j0 + cc - 3;
        wm[k]  = (l < HSZ);
        val[k] = wm[k] && ((unsigned)gi < (unsigned)Mn) && ((unsigned)gj < (unsigned)Nn);
        ldsoff[k] = r * HP + cc;
        goff[k]   = gi * Nn + gj;
    }

    const float* abase = a_in + ((size_t)(mb * Pn + pg * 4) * Cn + c) * IMG;
    float rv[6];
    #pragma unroll
    for (int k = 0; k < 6; ++k) rv[k] = val[k] ? abase[goff[k]] : 0.f;

    float acc00 = 0.f, acc01 = 0.f, acc10 = 0.f, acc11 = 0.f;

    #pragma unroll 1
    for (int pi = 0; pi < 4; ++pi) {
        float* bufc = buf[pi & 1];
        #pragma unroll
        for (int k = 0; k < 6; ++k) if (wm[k]) bufc[ldsoff[k]] = rv[k];
        if (pi < 3) {
            const float* apn = abase + (size_t)(pi + 1) * (Cn * IMG);
            #pragma unroll
            for (int k = 0; k < 6; ++k) rv[k] = val[k] ? apn[goff[k]] : 0.f;
        }
        __syncthreads();
        const float* bp = Bg + ((pg * 4 + pi) * Cn + c) * 49;
        float bv[49];
        #pragma unroll
        for (int k = 0; k < 49; ++k) bv[k] = bp[k];
        #pragma unroll
        for (int r = 0; r < 8; ++r) {
            float w[8];
            const float* rowp = bufc + (2 * ty + r) * HP + 2 * tx;
            #pragma unroll
            for (int k = 0; k < 4; ++k) {
                float2 t = *(const float2*)(rowp + 2 * k);
                w[2 * k] = t.x; w[2 * k + 1] = t.y;
            }
            if (r <= 6) {
                #pragma unroll
                for (int v = 0; v < 7; ++v) {
                    float b = bv[r * 7 + v];
                    acc00 += w[v]     * b;
                    acc01 += w[v + 1] * b;
                }
            }
            if (r >= 1) {
                #pragma unroll
                for (int v = 0; v < 7; ++v) {
                    float b = bv[(r - 1) * 7 + v];
                    acc10 += w[v]     * b;
                    acc11 += w[v + 1] * b;
                }
            }
        }
        // double-buffered: WAR protected by next iteration's barrier
    }
    float* out = Bap + pg * XSZ + cm * IMG;
    int oi = i0 + 2 * ty, oj = j0 + 2 * tx;
    { float2 st; st.x = acc00; st.y = acc01; *(float2*)(out + oi * Nn + oj) = st; }
    { float2 st; st.x = acc10; st.y = acc11; *(float2*)(out + (oi + 1) * Nn + oj) = st; }
}

// ---------------- K2: x update + r + v (y2 finalize folded in) ----------------
__global__ __launch_bounds__(256) void k_xup(const float* __restrict__ xb, const float* __restrict__ Bap,
                                             const float* __restrict__ y1, const float* __restrict__ y2T,
                                             const float* __restrict__ x0c, const float* __restrict__ fil,
                                             const float* __restrict__ gam1, const float* __restrict__ gam3,
                                             const float* __restrict__ scale2, int step,
                                             float* __restrict__ xa, float* __restrict__ rr,
                                             float* __restrict__ vv) {
    int idx = blockIdx.x * 256 + threadIdx.x;
    if (idx >= XSZ) return;
    float g1 = gam1[step];
    int j = idx & 255, i = (idx >> 8) & 255, cm = idx >> 16;
    int mb = cm / Cn, c = cm - mb * Cn;

    float A = 0.f, Bz = 0.f;      // step 0: y2_prev == 0
    if (step > 0) {
        float g3p = gam3[step - 1];
        float invp = 1.f / (g3p + EPSf);
        float sc = scale2[mb];
        A  = 1.f - g3p * invp * sc;
        Bz = -g3p * (1.f - sc);
    }

    const float* y10 = y1 + (mb * 2) * CIMG + c * IMG;
    const float* y11 = y10 + CIMG;
    int im1 = (i == 0) ? Mn - 1 : i - 1;
    int jm1 = (j == 0) ? Nn - 1 : j - 1;
    float dt = y10[im1 * Nn + j] - y10[i * Nn + j] + y11[i * Nn + jm1] - y11[i * Nn + j];

    const float* Tc = y2T + cm * IMG;
    float cf = 0.f;
    #pragma unroll
    for (int u = 0; u < 5; ++u) {
        int ii = i + 2 - u;
        if ((unsigned)ii >= (unsigned)Mn) continue;
        #pragma unroll
        for (int v = 0; v < 5; ++v) {
            int jj = j + 2 - v;
            if ((unsigned)jj >= (unsigned)Nn) continue;
            cf += fil[u * 5 + v] * Tc[ii * Nn + jj];
        }
    }
    cf = A * cf + Bz * x0c[idx];   // conv(y2_aft) = A*conv(T) + Bz*conv(z)

    float bav = 0.f;
    #pragma unroll
    for (int k = 0; k < 8; ++k) bav += Bap[k * XSZ + idx];
    float xv = xb[idx];
    float xn = xv - g1 * (xv - bav + dt + cf);
    xn = fminf(fmaxf(xn, 0.f), 1.f);
    xa[idx] = xn;
    rr[idx] = xv - bav;
    vv[idx] = 2.f * xn - xv;
}

// ---------------- K3: a update (64x32 tile, 4x2/thread, one p per block)
//                  + sequential y1/y2 chunk on blocks 0..1535 ----------------
__global__ __launch_bounds__(256) void k_aup(const float* __restrict__ a_in, float* __restrict__ a_out,
                                             const float* __restrict__ rr, const float* __restrict__ Bg,
                                             float* __restrict__ y1, float* __restrict__ y2T,
                                             const float* __restrict__ vv, const float* __restrict__ fil,
                                             const float* __restrict__ z,
                                             const float* __restrict__ lam1, const float* __restrict__ lam2,
                                             const float* __restrict__ gam2, const float* __restrict__ gam3,
                                             const float* __restrict__ scale2, int step,
                                             float* __restrict__ partial) {
    __shared__ float rs[70 * ASTR];
    int blk = blockIdx.x;
    int tid = threadIdx.x;

    // ============ part 1: aup tile ============
    {
        int p    = blk & 31;
        int tile = (blk >> 5) & 31;    // 4 ti x 8 tj
        int cm   = blk >> 10;          // 0..5
        int c = cm % Cn, mb = cm / Cn;
        int i0 = (tile >> 3) * 64, j0 = (tile & 7) * 32;
        int tx = tid & 15, ty = tid >> 4;

        int oi = i0 + 4 * ty, oj = j0 + 2 * tx;
        size_t off0 = ((size_t)(mb * Pn + p) * Cn + c) * IMG + (size_t)oi * Nn + oj;

        // issue the a-loads first: latency hides under staging
        float2 cur[4];
        #pragma unroll
        for (int ri = 0; ri < 4; ++ri) cur[ri] = *(const float2*)(a_in + off0 + (size_t)ri * Nn);

        const float* rp = rr + cm * IMG;
        for (int l = tid; l < 70 * 38; l += 256) {
            int r = l / 38, cc = l - r * 38;
            int gi = i0 + r - 3, gj = j0 + cc - 3;
            float v = 0.f;
            if ((unsigned)gi < (unsigned)Mn && (unsigned)gj < (unsigned)Nn) v = rp[gi * Nn + gj];
            rs[r * ASTR + cc] = v;
        }
        __syncthreads();

        const float* bp = Bg + (p * Cn + c) * 49;   // uniform: s_loads
        float acc[8];
        #pragma unroll
        for (int k = 0; k < 8; ++k) acc[k] = 0.f;

        #pragma unroll
        for (int r = 0; r < 10; ++r) {
            float w[8];
            const float* rowp = rs + (4 * ty + r) * ASTR + 2 * tx;
            #pragma unroll
            for (int k = 0; k < 4; ++k) {
                float2 t = *(const float2*)(rowp + 2 * k);
                w[2 * k] = t.x; w[2 * k + 1] = t.y;
            }
            #pragma unroll
            for (int ri = 0; ri < 4; ++ri) {
                int u = r - ri;
                if (u >= 0 && u <= 6) {
                    #pragma unroll
                    for (int v = 0; v < 7; ++v) {
                        float b = bp[(6 - u) * 7 + (6 - v)];   // flipped: true convolution
                        acc[ri * 2]     += w[v]     * b;
                        acc[ri * 2 + 1] += w[v + 1] * b;
                    }
                }
            }
        }

        float g2 = gam2[step], thr = g2 * lam1[step];
        #pragma unroll
        for (int ri = 0; ri < 4; ++ri) {
            float2 s;
            s.x = cur[ri].x + g2 * acc[ri * 2];
            s.y = cur[ri].y + g2 * acc[ri * 2 + 1];
            s.x = copysignf(fmaxf(fabsf(s.x) - thr, 0.f), s.x);
            s.y = copysignf(fmaxf(fabsf(s.y) - thr, 0.f), s.y);
            *(float2*)(a_out + off0 + (size_t)ri * Nn) = s;
        }
    }

    // ============ part 2: y1/y2 chunk (blocks 0..1535 only) ============
    if (blk >= XSZ / 256) return;
    __syncthreads();               // rs reused as reduction buffer
    {
        float* red = rs;
        int idx = blk * 256 + tid;
        float g3 = gam3[step], l2v = lam2[step];
        int j = idx & 255, i = (idx >> 8) & 255, cm = idx >> 16;
        int mb = cm / Cn, c = cm - mb * Cn;
        const float* vc = vv + cm * IMG;

        float A = 0.f, Bz = 0.f;      // step 0: y2_prev == 0
        if (step > 0) {
            float g3p = gam3[step - 1];
            float invp = 1.f / (g3p + EPSf);
            float sc = scale2[mb];
            A  = 1.f - g3p * invp * sc;
            Bz = -g3p * (1.f - sc);
        }

        int ip1 = (i == Mn - 1) ? 0 : i + 1;
        int jp1 = (j == Nn - 1) ? 0 : j + 1;
        float vij = vc[i * Nn + j];
        float d0 = vc[ip1 * Nn + j] - vij;
        float d1 = vc[i * Nn + jp1] - vij;
        float* y10 = y1 + (mb * 2) * CIMG + c * IMG + i * Nn + j;
        float* y11 = y10 + CIMG;
        float t0 = *y10 + g3 * d0;
        float t1 = *y11 + g3 * d1;
        float inv = 1.f / (g3 + EPSf);
        float w0 = t0 * inv, w1 = t1 * inv;
        float nrm = sqrtf(w0 * w0 + w1 * w1);
        float fac = fmaxf(1.f - (l2v * inv) / fmaxf(nrm, EPSf), 0.f);
        *y10 = t0 - g3 * (w0 * fac);
        *y11 = t1 - g3 * (w1 * fac);

        float cf = 0.f;
        #pragma unroll
        for (int u = 0; u < 5; ++u) {
            int ii2 = i + u - 2;
            if ((unsigned)ii2 >= (unsigned)Mn) continue;
            #pragma unroll
            for (int v = 0; v < 5; ++v) {
                int jj2 = j + v - 2;
                if ((unsigned)jj2 >= (unsigned)Nn) continue;
                cf += fil[u * 5 + v] * vc[ii2 * Nn + jj2];
            }
        }
        float zv = z[idx];
        float t = A * y2T[idx] + Bz * zv + g3 * cf;
        y2T[idx] = t;
        float d = t * inv - zv;
        red[tid] = d * d;
        __syncthreads();
        #pragma unroll
        for (int s = 128; s > 0; s >>= 1) {
            if (tid < s) red[tid] += red[tid + s];
            __syncthreads();
        }
        if (tid == 0) partial[blk] = red[0];
    }
}

extern "C" void kernel_launch(void* const* d_in, const int* in_sizes, int n_in,
                              void* d_out, int out_size, void* d_ws, size_t ws_size,
                              hipStream_t stream) {
    const float* z      = (const float*)d_in[0];
    const float* a_init = (const float*)d_in[1];
    const float* B      = (const float*)d_in[2];
    const float* fil    = (const float*)d_in[3];
    const float* lam1   = (const float*)d_in[4];
    const float* lam2   = (const float*)d_in[5];
    const float* gam1   = (const float*)d_in[6];
    const float* gam2   = (const float*)d_in[7];
    const float* gam3   = (const float*)d_in[8];

    float* ws = (float*)d_ws;
    float* a      = ws;                    // ASZ
    float* xA     = a + ASZ;               // XSZ
    float* xB     = xA + XSZ;              // XSZ
    float* x0c    = xB + XSZ;              // XSZ (persistent conv_fil(z))
    float* Bap    = x0c + XSZ;             // 8*XSZ
    float* rr     = Bap + 8 * XSZ;         // XSZ
    float* vv     = rr + XSZ;              // XSZ
    float* y1     = vv + XSZ;              // 2*XSZ
    float* y2T    = y1 + 2 * XSZ;          // XSZ (pre-finalize accumulator T_s)
    float* part   = y2T + XSZ;             // 1536
    float* scale2 = part + 1536;           // 2

    // init
    hipMemsetAsync(y1, 0, (size_t)2 * XSZ * sizeof(float), stream);
    hipMemsetAsync(part, 0, 1536 * sizeof(float), stream);
    k_x0<<<XSZ / 256, 256, 0, stream>>>(z, fil, xA, x0c);

    float* xin = xA;
    float* xout = xB;
    for (int s = 0; s < NSTEP; ++s) {
        const float* a_src = (s == 0) ? a_init : a;
        k_conv<<<NCONV + 2, 256, 0, stream>>>(a_src, B, Bap, part, scale2);
        k_xup<<<XSZ / 256, 256, 0, stream>>>(xin, Bap, y1, y2T, x0c, fil, gam1, gam3, scale2, s,
                                             xout, rr, vv);
        if (s < NSTEP - 1) {
            k_aup<<<NAUP, 256, 0, stream>>>(a_src, a, rr, B, y1, y2T, vv, fil, z,
                                            lam1, lam2, gam2, gam3, scale2, s, part);
        }
        float* t = xin; xin = xout; xout = t;
    }

    hipMemcpyAsync(d_out, xin, (size_t)XSZ * sizeof(float), hipMemcpyDeviceToDevice, stream);
}